// Round 19
// baseline (194.891 us; speedup 1.0000x reference)
//
#include <hip/hip_runtime.h>

typedef __attribute__((ext_vector_type(8))) short bf16x8;
typedef __attribute__((ext_vector_type(4))) float f32x4;
typedef __attribute__((ext_vector_type(16))) float f32x16;
typedef unsigned int u32;

#define S_LEN 2048
#define HIDDEN 2048
#define NH 16
#define NKV 2
#define DH 128
#define BATCH 2

__device__ __forceinline__ short f2bf(float f) {
  union { float f; u32 u; } x; x.f = f;
  u32 r = x.u + 0x7fffu + ((x.u >> 16) & 1u);
  return (short)(r >> 16);
}
__device__ __forceinline__ float bf2f(short s) {
  union { u32 u; float f; } x; x.u = ((u32)(unsigned short)s) << 16;
  return x.f;
}
__device__ __forceinline__ void load_lds_16(const void* g, void* l) {
  __builtin_amdgcn_global_load_lds(
      (const __attribute__((address_space(1))) u32*)g,
      (__attribute__((address_space(3))) u32*)l, 16, 0, 0);
}
__device__ __forceinline__ u32 cvt_pk_bf16(float lo, float hi) {
  u32 d;
  asm("v_cvt_pk_bf16_f32 %0, %1, %2" : "=v"(d) : "v"(lo), "v"(hi));
  return d;
}

// ---------------- fused f32->bf16 converts + bias concat (1 launch) ----------------
__global__ void megacvt_k(const float* __restrict__ hid, const float* __restrict__ qw,
                          const float* __restrict__ kw, const float* __restrict__ vw,
                          const float* __restrict__ ow,
                          const float* __restrict__ qb, const float* __restrict__ kb,
                          const float* __restrict__ vb,
                          short* __restrict__ x_bf, short* __restrict__ w_bf,
                          short* __restrict__ ow_bf, float* __restrict__ biasc) {
  const int blk = blockIdx.x;
  if (blk < 17408) {
    const float* src;
    short* dst;
    int i;
    if (blk < 8192)       { src = hid; dst = x_bf;                i = blk * 256 + threadIdx.x; }
    else if (blk < 12288) { src = qw;  dst = w_bf;                i = (blk - 8192) * 256 + threadIdx.x; }
    else if (blk < 12800) { src = kw;  dst = w_bf + 2048 * 2048;  i = (blk - 12288) * 256 + threadIdx.x; }
    else if (blk < 13312) { src = vw;  dst = w_bf + 2304 * 2048;  i = (blk - 12800) * 256 + threadIdx.x; }
    else                  { src = ow;  dst = ow_bf;               i = (blk - 13312) * 256 + threadIdx.x; }
    const float4 v = ((const float4*)src)[i];
    short4 o;
    o.x = f2bf(v.x); o.y = f2bf(v.y); o.z = f2bf(v.z); o.w = f2bf(v.w);
    ((short4*)dst)[i] = o;
  } else {
    const int i = (blk - 17408) * 256 + threadIdx.x;   // 0..2559
    if (i < 2048) biasc[i] = qb[i];
    else if (i < 2304) biasc[i] = kb[i - 2048];
    else if (i < 2560) biasc[i] = vb[i - 2304];
  }
}

// ---------------- NT GEMM, dbuf + counted vmcnt (R14/R16-proven body) ------------
template<int MODE>
__global__ __launch_bounds__(256, 4) void gemm_nt_k(
    const short* __restrict__ A, const short* __restrict__ Bw,
    const float* __restrict__ bias, const float* __restrict__ cosb,
    const float* __restrict__ sinb,
    float* __restrict__ Cf32, short* __restrict__ Qo,
    short* __restrict__ Ko, short* __restrict__ VT,
    int M, int N, int K) {
  __shared__ short As[2][128 * 32];
  __shared__ short Bs[2][128 * 32];
  const int tid = threadIdx.x;
  const int lane = tid & 63;
  const int w = tid >> 6;
  const int orig = blockIdx.x;
  const int xcd = orig & 7, idx = orig >> 3;
  const int rx = xcd & 3, ry = xcd >> 2;
  int bn, bm;
  if (MODE == 2) { bn = ry * 10 + (idx >> 3); bm = rx * 8 + (idx & 7); }  // 20x32
  else           { bn = ry * 8  + (idx >> 3); bm = rx * 8 + (idx & 7); }  // 16x32
  const int wm = (w >> 1) * 64;
  const int l15 = lane & 15, l4 = lane >> 4;
  f32x4 acc[4][4] = {};

  const int sr = lane >> 2;
  const int sp = lane & 3;
  const int nk = K >> 5;

  auto stage = [&](int bi, int kt) {
    const int k0 = kt << 5;
#pragma unroll
    for (int r = 0; r < 2; ++r) {
      const int kb = w + r * 4;
      const int row = kb * 16 + sr;
      const int gcol = (sp ^ ((row >> 1) & 3)) * 8;
      load_lds_16(A + (size_t)(bm * 128 + row) * K + k0 + gcol, &As[bi][kb * 512]);
      load_lds_16(Bw + (size_t)(bn * 128 + row) * K + k0 + gcol, &Bs[bi][kb * 512]);
    }
  };

  stage(0, 0);
  int cur = 0;
  for (int kt = 0; kt < nk; ++kt) {
    if (kt + 1 < nk) {
      stage(cur ^ 1, kt + 1);
      asm volatile("s_waitcnt vmcnt(4)" ::: "memory");
    } else {
      asm volatile("s_waitcnt vmcnt(0)" ::: "memory");
    }
    __builtin_amdgcn_s_barrier();
    asm volatile("" ::: "memory");
    bf16x8 af[4], bfr[4];
#pragma unroll
    for (int i = 0; i < 4; ++i) {
      const int ra = wm + i * 16 + l15;
      af[i] = *(const bf16x8*)&As[cur][ra * 32 + (l4 ^ ((ra >> 1) & 3)) * 8];
      const int rb = (w & 1) * 32 + (i & 1) * 16 + (i >> 1) * 64 + l15;  // paired cols
      bfr[i] = *(const bf16x8*)&Bs[cur][rb * 32 + (l4 ^ ((rb >> 1) & 3)) * 8];
    }
#pragma unroll
    for (int i = 0; i < 4; ++i)
#pragma unroll
      for (int j = 0; j < 4; ++j)
        acc[i][j] = __builtin_amdgcn_mfma_f32_16x16x32_bf16(af[i], bfr[j], acc[i][j], 0, 0, 0);
    asm volatile("" ::: "memory");
    __builtin_amdgcn_s_barrier();
    cur ^= 1;
  }

  if (MODE == 0) {
#pragma unroll
    for (int j = 0; j < 4; ++j) {
      const int n = bn * 128 + (w & 1) * 32 + (j & 1) * 16 + (j >> 1) * 64 + l15;
#pragma unroll
      for (int i = 0; i < 4; ++i) {
        const int mbase = bm * 128 + wm + i * 16 + l4 * 4;
#pragma unroll
        for (int r = 0; r < 4; ++r)
          Cf32[(size_t)(mbase + r) * N + n] = acc[i][j][r];
      }
    }
  } else {
    const int b = bm >> 4;
    if (bn < 18) {
      const bool isq = (bn < 16);
      const float sc = isq ? (0.08838834764831845f * 1.4426950408889634f) : 1.f;
#pragma unroll
      for (int j = 0; j < 2; ++j) {
        const int d = (w & 1) * 32 + j * 16 + l15;        // 0..63
        const int n1 = bn * 128 + d;
        const float b1 = bias[n1];
        const float b2 = bias[n1 + 64];
        short* base;
        if (isq) base = Qo + ((size_t)(b * NH + bn) * S_LEN) * DH;
        else     base = Ko + ((size_t)(b * NKV + (bn - 16)) * S_LEN) * DH;
#pragma unroll
        for (int i = 0; i < 4; ++i) {
          const int sb = (bm & 15) * 128 + wm + i * 16 + l4 * 4;
#pragma unroll
          for (int r = 0; r < 4; ++r) {
            const int s = sb + r;
            const float c  = cosb[s * 128 + d];
            const float sn = sinb[s * 128 + d];
            const float v1 = acc[i][j][r] + b1;
            const float v2 = acc[i][j + 2][r] + b2;
            base[(size_t)s * DH + d]      = f2bf((v1 * c - v2 * sn) * sc);
            base[(size_t)s * DH + d + 64] = f2bf((v2 * c + v1 * sn) * sc);
          }
        }
      }
    } else {
      const int kv = bn - 18;
      short* vbase = VT + (size_t)(b * NKV + kv) * DH * S_LEN;
#pragma unroll
      for (int j = 0; j < 4; ++j) {
        const int d = (w & 1) * 32 + (j & 1) * 16 + (j >> 1) * 64 + l15;  // 0..127
        const float bv = bias[bn * 128 + d];
#pragma unroll
        for (int i = 0; i < 4; ++i) {
          const int sb = (bm & 15) * 128 + wm + i * 16 + l4 * 4;
          short4 st;
          st.x = f2bf(acc[i][j][0] + bv);
          st.y = f2bf(acc[i][j][1] + bv);
          st.z = f2bf(acc[i][j][2] + bv);
          st.w = f2bf(acc[i][j][3] + bv);
          *(short4*)(vbase + (size_t)d * S_LEN + sb) = st;
        }
      }
    }
  }
}

// ---------------- causal GQA flash attention, paired q-tiles + NS=3 kv split -----
// 768 blocks = (a 0..7, bh 0..31, s 0..2) = exactly 3 blocks/CU, ONE round.
// Block runs q-tile a then q-tile 15-a serially (uniform ~11-12 iters total).
// Inner loop = R17-proven: K single-buffer + V double-buffer, 2 barriers/iter.
// __syncthreads() between streams orders LDS reuse across lagging waves.
template<int NS>
__global__ __launch_bounds__(256, 2) void attn_k(
    const short* __restrict__ Qb, const short* __restrict__ Kb,
    const short* __restrict__ VTb, short* __restrict__ Opart,
    float2* __restrict__ ML) {
  __shared__ short Ks[64 * 128];
  __shared__ short Vs[2][128 * 64];
  const int tid = threadIdx.x, lane = tid & 63, w = tid >> 6;
  const int bid = blockIdx.x;            // 0..256*NS-1
  const int s = bid % NS;
  const int rr = bid / NS;
  const int bh = rr & 31;
  const int a = rr >> 5;                 // 0..7
  const int b = bh >> 4, h = bh & 15;
  const int kvh = h >> 3;
  const int l31 = lane & 31, hi = lane >> 5;

  const short* Kbase = Kb + (size_t)(b * NKV + kvh) * S_LEN * DH;
  const short* Vbase = VTb + (size_t)(b * NKV + kvh) * DH * S_LEN;

  auto stageK = [&](int tile) {
    const int kv0 = tile << 6;
#pragma unroll
    for (int r = 0; r < 4; ++r) {
      const int kb = r * 4 + w;
      const int krow = kb * 4 + (lane >> 4);
      const int gs = ((lane & 15) ^ (krow & 15)) * 8;
      load_lds_16(Kbase + (size_t)(kv0 + krow) * DH + gs, &Ks[kb * 512]);
    }
  };
  auto stageV = [&](int bi, int tile) {
    const int kv0 = tile << 6;
#pragma unroll
    for (int r = 0; r < 4; ++r) {
      const int kb = r * 4 + w;
      const int vrow = kb * 8 + (lane >> 3);
      const int gs = ((lane & 7) ^ (vrow & 7)) * 8;
      load_lds_16(Vbase + (size_t)vrow * S_LEN + kv0 + gs, &Vs[bi][kb * 512]);
    }
  };

  for (int si = 0; si < 2; ++si) {
    const int x = si ? (15 - a) : a;     // q-tile
    const int qw = x * 128 + w * 32;
    const int q = qw + l31;
    const int num = 2 * x + 2 - s;
    const int cnt = num > 0 ? (num + NS - 1) / NS : 0;

    f32x16 o[4] = {};  // O^T tiles: o[dt][r] = O[q][d=(r&3)+8*(r>>2)+4hi+32dt]
    float m_r = -1e30f, l_r = 0.f;

    if (cnt > 0) {
      bf16x8 qf[8];
      {
        const short* qrow = Qb + ((size_t)(b * NH + h) * S_LEN + q) * DH;
#pragma unroll
        for (int ss = 0; ss < 8; ++ss)
          qf[ss] = *(const bf16x8*)(qrow + ss * 16 + hi * 8);
      }
      stageK(s);        // K_0 (4 loads, oldest)
      stageV(0, s);     // V_0 (4 loads)
      int cur = 0;
      for (int j = 0; j < cnt; ++j) {
        const int tile = s + NS * j;
        const int kv0 = tile << 6;
        const bool more = (j + 1 < cnt);
        const bool active = (kv0 <= qw + 31);
        asm volatile("s_waitcnt vmcnt(4)" ::: "memory");
        __builtin_amdgcn_s_barrier();                     // bar1: K_j global
        asm volatile("" ::: "memory");
        f32x16 sc0 = {}, sc1 = {};
        if (active) {
          __builtin_amdgcn_s_setprio(1);
#pragma unroll
          for (int ss = 0; ss < 8; ++ss) {
            const int sl = ((2 * ss + hi) ^ (l31 & 15)) * 8;
            const bf16x8 kf0 = *(const bf16x8*)&Ks[l31 * 128 + sl];
            const bf16x8 kf1 = *(const bf16x8*)&Ks[(l31 + 32) * 128 + sl];
            sc0 = __builtin_amdgcn_mfma_f32_32x32x16_bf16(kf0, qf[ss], sc0, 0, 0, 0);
            sc1 = __builtin_amdgcn_mfma_f32_32x32x16_bf16(kf1, qf[ss], sc1, 0, 0, 0);
          }
          __builtin_amdgcn_s_setprio(0);
        }
        asm volatile("s_waitcnt vmcnt(0)" ::: "memory");
        asm volatile("" ::: "memory");
        __builtin_amdgcn_s_barrier();                     // bar2: K free + V_j global
        if (more) {
          stageK(tile + NS);
          stageV(cur ^ 1, tile + NS);
        }
        if (active) {
          if (kv0 + 63 > qw) {
#pragma unroll
            for (int r = 0; r < 16; ++r) {
              const int kva = kv0 + (r & 3) + 8 * (r >> 2) + 4 * hi;
              if (kva > q) sc0[r] = -1e30f;
              if (kva + 32 > q) sc1[r] = -1e30f;
            }
          }
          float mx[16];
#pragma unroll
          for (int r = 0; r < 16; ++r) mx[r] = fmaxf(sc0[r], sc1[r]);
#pragma unroll
          for (int st = 8; st >= 1; st >>= 1)
#pragma unroll
            for (int r = 0; r < st; ++r) mx[r] = fmaxf(mx[r], mx[r + st]);
          const float pm = fmaxf(mx[0], __shfl_xor(mx[0], 32));
          if (__any(pm > m_r + 8.f)) {   // T13 defer-rescale
            const float nm = fmaxf(m_r, pm);
            const float fr = exp2f(m_r - nm);
            l_r *= fr;
#pragma unroll
            for (int dt = 0; dt < 4; ++dt)
#pragma unroll
              for (int r = 0; r < 16; ++r)
                o[dt][r] *= fr;
            m_r = nm;
          }
#pragma unroll
          for (int r = 0; r < 16; ++r) {
            sc0[r] = exp2f(sc0[r] - m_r);
            sc1[r] = exp2f(sc1[r] - m_r);
          }
          float sm[16];
#pragma unroll
          for (int r = 0; r < 16; ++r) sm[r] = sc0[r] + sc1[r];
#pragma unroll
          for (int st = 8; st >= 1; st >>= 1)
#pragma unroll
            for (int r = 0; r < st; ++r) sm[r] += sm[r + st];
          l_r += sm[0] + __shfl_xor(sm[0], 32);
          u32 e0 = cvt_pk_bf16(sc0[0], sc0[1]),  e1 = cvt_pk_bf16(sc0[2], sc0[3]);
          u32 e2 = cvt_pk_bf16(sc0[4], sc0[5]),  e3 = cvt_pk_bf16(sc0[6], sc0[7]);
          u32 e4 = cvt_pk_bf16(sc0[8], sc0[9]),  e5 = cvt_pk_bf16(sc0[10], sc0[11]);
          u32 e6 = cvt_pk_bf16(sc0[12], sc0[13]), e7 = cvt_pk_bf16(sc0[14], sc0[15]);
          u32 f0 = cvt_pk_bf16(sc1[0], sc1[1]),  f1 = cvt_pk_bf16(sc1[2], sc1[3]);
          u32 f2 = cvt_pk_bf16(sc1[4], sc1[5]),  f3 = cvt_pk_bf16(sc1[6], sc1[7]);
          u32 f4 = cvt_pk_bf16(sc1[8], sc1[9]),  f5 = cvt_pk_bf16(sc1[10], sc1[11]);
          u32 f6 = cvt_pk_bf16(sc1[12], sc1[13]), f7 = cvt_pk_bf16(sc1[14], sc1[15]);
          asm("v_permlane32_swap_b32 %0, %1" : "+v"(e0), "+v"(e2));
          asm("v_permlane32_swap_b32 %0, %1" : "+v"(e1), "+v"(e3));
          asm("v_permlane32_swap_b32 %0, %1" : "+v"(e4), "+v"(e6));
          asm("v_permlane32_swap_b32 %0, %1" : "+v"(e5), "+v"(e7));
          asm("v_permlane32_swap_b32 %0, %1" : "+v"(f0), "+v"(f2));
          asm("v_permlane32_swap_b32 %0, %1" : "+v"(f1), "+v"(f3));
          asm("v_permlane32_swap_b32 %0, %1" : "+v"(f4), "+v"(f6));
          asm("v_permlane32_swap_b32 %0, %1" : "+v"(f5), "+v"(f7));
          union { u32 u[4]; bf16x8 v; } pk0, pk1, pk2, pk3;
          pk0.u[0] = e0; pk0.u[1] = e1; pk0.u[2] = e2; pk0.u[3] = e3;  // kv 0..15
          pk1.u[0] = e4; pk1.u[1] = e5; pk1.u[2] = e6; pk1.u[3] = e7;  // kv 16..31
          pk2.u[0] = f0; pk2.u[1] = f1; pk2.u[2] = f2; pk2.u[3] = f3;  // kv 32..47
          pk3.u[0] = f4; pk3.u[1] = f5; pk3.u[2] = f6; pk3.u[3] = f7;  // kv 48..63
          const bf16x8 pa[4] = {pk0.v, pk1.v, pk2.v, pk3.v};
          __builtin_amdgcn_s_setprio(1);
#pragma unroll
          for (int ss = 0; ss < 4; ++ss) {
#pragma unroll
            for (int dt = 0; dt < 4; ++dt) {
              const int row = dt * 32 + l31;
              const int sl = ((2 * ss + hi) ^ (l31 & 7)) * 8;
              const bf16x8 vf = *(const bf16x8*)&Vs[cur][row * 64 + sl];
              o[dt] = __builtin_amdgcn_mfma_f32_32x32x16_bf16(vf, pa[ss], o[dt], 0, 0, 0);
            }
          }
          __builtin_amdgcn_s_setprio(0);
        }
        cur ^= 1;
      }
    }

    // ---- epilogue: store UNNORMALIZED partial + (m,l) ----
    const int T = (bh * 16 + x) * NS + s;
    const int ql = w * 32 + l31;
    short* orow = Opart + (size_t)T * 16384 + ql * 128;
#pragma unroll
    for (int dt = 0; dt < 4; ++dt)
#pragma unroll
      for (int gg = 0; gg < 4; ++gg) {
        short4 st;
        st.x = f2bf(o[dt][4 * gg + 0]);
        st.y = f2bf(o[dt][4 * gg + 1]);
        st.z = f2bf(o[dt][4 * gg + 2]);
        st.w = f2bf(o[dt][4 * gg + 3]);
        *(short4*)(orow + dt * 32 + 8 * gg + 4 * hi) = st;
      }
    if (hi == 0) ML[T * 128 + ql] = make_float2(m_r, l_r);
    __syncthreads();   // LDS reuse fence between streams (lgkmcnt drained)
  }
}

// ---------------- combine the NS kv-split partials ----------------
template<int NS>
__global__ void combine_k(const short* __restrict__ Opart,
                          const float2* __restrict__ ML,
                          short* __restrict__ att_o) {
  const int t = blockIdx.x * 256 + threadIdx.x;   // 2^20 threads
  const int d8 = t & 15;
  const int h  = (t >> 4) & 15;
  const int q  = (t >> 8) & 2047;
  const int b  = t >> 19;
  const int bh = b * 16 + h;
  const int x = q >> 7, ql = q & 127;
  const int T0 = (bh * 16 + x) * NS;
  float2 a[NS];
  float ms = -1e30f;
#pragma unroll
  for (int i = 0; i < NS; ++i) {
    a[i] = ML[(T0 + i) * 128 + ql];
    ms = fmaxf(ms, a[i].x);
  }
  float wgt[NS];
  float den = 0.f;
#pragma unroll
  for (int i = 0; i < NS; ++i) {
    wgt[i] = exp2f(a[i].x - ms);
    den += a[i].y * wgt[i];
  }
  const float inv = 1.f / den;
  float acc[8] = {};
#pragma unroll
  for (int i = 0; i < NS; ++i) {
    const bf16x8 oi = *(const bf16x8*)(Opart + (size_t)(T0 + i) * 16384 + ql * 128 + d8 * 8);
#pragma unroll
    for (int e = 0; e < 8; ++e)
      acc[e] += bf2f(oi[e]) * wgt[i];
  }
  bf16x8 res;
#pragma unroll
  for (int e = 0; e < 8; ++e)
    res[e] = f2bf(acc[e] * inv);
  *(bf16x8*)(att_o + (size_t)(b * S_LEN + q) * (NH * DH) + h * DH + d8 * 8) = res;
}

// ---------------- launch ----------------
extern "C" void kernel_launch(void* const* d_in, const int* in_sizes, int n_in,
                              void* d_out, int out_size, void* d_ws, size_t ws_size,
                              hipStream_t stream) {
  const float* hid  = (const float*)d_in[0];
  const float* cosb = (const float*)d_in[1];
  const float* sinb = (const float*)d_in[2];
  const float* q_w  = (const float*)d_in[3];
  const float* q_b  = (const float*)d_in[4];
  const float* k_w  = (const float*)d_in[5];
  const float* k_b  = (const float*)d_in[6];
  const float* v_w  = (const float*)d_in[7];
  const float* v_b  = (const float*)d_in[8];
  const float* o_w  = (const float*)d_in[9];
  (void)in_sizes; (void)n_in; (void)out_size; (void)ws_size;

  char* ws = (char*)d_ws;
  // NS=3 layout (81.3 MB total; ws >= 94.4 MB proven in R8):
  //   [0        .. 50331648)  Opart [1536][16384] bf16  (attn phase)
  //   [0        .. 16777216)  x_bf  (phase 1 overlay, dead before attn)
  //   [16777216 .. 27262976)  w_bf  (phase 1 overlay, dead before attn)
  //   [50331648 .. 51904512)  MLbuf [1536][128] float2
  //   [51904512 .. 68681728)  q_bf (roped Q) -> reused as att_o after attn
  //   [68681728 .. 70778880)  k_bf
  //   [70778880 .. 72876032)  vT_bf
  //   [72876032 .. 81264640)  ow_bf
  //   [81264640 .. 81274880)  biasc
  short*  x_bf   = (short*)(ws + 0);
  short*  w_bf   = (short*)(ws + 16777216);
  short*  Opart  = (short*)(ws + 0);
  float2* MLbuf  = (float2*)(ws + 50331648);
  short*  q_bf   = (short*)(ws + 51904512);
  short*  att_o  = (short*)(ws + 51904512);   // overlays q_bf (dead after attn)
  short*  k_bf   = (short*)(ws + 68681728);
  short*  vT_bf  = (short*)(ws + 70778880);
  short*  ow_bf  = (short*)(ws + 72876032);
  float*  biasc  = (float*)(ws + 81264640);

  hipLaunchKernelGGL(megacvt_k, dim3(17418), dim3(256), 0, stream,
                     hid, q_w, k_w, v_w, o_w, q_b, k_b, v_b, x_bf, w_bf, ow_bf, biasc);
  hipLaunchKernelGGL((gemm_nt_k<2>), dim3(640), dim3(256), 0, stream,
                     x_bf, w_bf, biasc, cosb, sinb,
                     (float*)nullptr, q_bf, k_bf, vT_bf, 4096, 2560, 2048);
  hipLaunchKernelGGL(attn_k<3>, dim3(768), dim3(256), 0, stream,
                     q_bf, k_bf, vT_bf, Opart, MLbuf);
  hipLaunchKernelGGL(combine_k<3>, dim3(4096), dim3(256), 0, stream, Opart, MLbuf, att_o);
  hipLaunchKernelGGL((gemm_nt_k<0>), dim3(512), dim3(256), 0, stream,
                     att_o, ow_bf, (const float*)nullptr, (const float*)nullptr,
                     (const float*)nullptr, (float*)d_out,
                     (short*)nullptr, (short*)nullptr, (short*)nullptr, 4096, 2048, 2048);
}

// Round 20
// 183.704 us; speedup vs baseline: 1.0609x; 1.0609x over previous
//
#include <hip/hip_runtime.h>

typedef __attribute__((ext_vector_type(8))) short bf16x8;
typedef __attribute__((ext_vector_type(4))) float f32x4;
typedef __attribute__((ext_vector_type(16))) float f32x16;
typedef unsigned int u32;

#define S_LEN 2048
#define HIDDEN 2048
#define NH 16
#define NKV 2
#define DH 128
#define BATCH 2

__device__ __forceinline__ short f2bf(float f) {
  union { float f; u32 u; } x; x.f = f;
  u32 r = x.u + 0x7fffu + ((x.u >> 16) & 1u);
  return (short)(r >> 16);
}
__device__ __forceinline__ float bf2f(short s) {
  union { u32 u; float f; } x; x.u = ((u32)(unsigned short)s) << 16;
  return x.f;
}
__device__ __forceinline__ void load_lds_16(const void* g, void* l) {
  __builtin_amdgcn_global_load_lds(
      (const __attribute__((address_space(1))) u32*)g,
      (__attribute__((address_space(3))) u32*)l, 16, 0, 0);
}
__device__ __forceinline__ u32 cvt_pk_bf16(float lo, float hi) {
  u32 d;
  asm("v_cvt_pk_bf16_f32 %0, %1, %2" : "=v"(d) : "v"(lo), "v"(hi));
  return d;
}

// ---------------- fused f32->bf16 converts + bias concat (1 launch) ----------------
__global__ void megacvt_k(const float* __restrict__ hid, const float* __restrict__ qw,
                          const float* __restrict__ kw, const float* __restrict__ vw,
                          const float* __restrict__ ow,
                          const float* __restrict__ qb, const float* __restrict__ kb,
                          const float* __restrict__ vb,
                          short* __restrict__ x_bf, short* __restrict__ w_bf,
                          short* __restrict__ ow_bf, float* __restrict__ biasc) {
  const int blk = blockIdx.x;
  if (blk < 17408) {
    const float* src;
    short* dst;
    int i;
    if (blk < 8192)       { src = hid; dst = x_bf;                i = blk * 256 + threadIdx.x; }
    else if (blk < 12288) { src = qw;  dst = w_bf;                i = (blk - 8192) * 256 + threadIdx.x; }
    else if (blk < 12800) { src = kw;  dst = w_bf + 2048 * 2048;  i = (blk - 12288) * 256 + threadIdx.x; }
    else if (blk < 13312) { src = vw;  dst = w_bf + 2304 * 2048;  i = (blk - 12800) * 256 + threadIdx.x; }
    else                  { src = ow;  dst = ow_bf;               i = (blk - 13312) * 256 + threadIdx.x; }
    const float4 v = ((const float4*)src)[i];
    short4 o;
    o.x = f2bf(v.x); o.y = f2bf(v.y); o.z = f2bf(v.z); o.w = f2bf(v.w);
    ((short4*)dst)[i] = o;
  } else {
    const int i = (blk - 17408) * 256 + threadIdx.x;   // 0..2559
    if (i < 2048) biasc[i] = qb[i];
    else if (i < 2304) biasc[i] = kb[i - 2048];
    else if (i < 2560) biasc[i] = vb[i - 2304];
  }
}

// ---------------- NT GEMM, dbuf + counted vmcnt (R14/R16-proven body) ------------
template<int MODE>
__global__ __launch_bounds__(256, 4) void gemm_nt_k(
    const short* __restrict__ A, const short* __restrict__ Bw,
    const float* __restrict__ bias, const float* __restrict__ cosb,
    const float* __restrict__ sinb,
    float* __restrict__ Cf32, short* __restrict__ Qo,
    short* __restrict__ Ko, short* __restrict__ VT,
    int M, int N, int K) {
  __shared__ short As[2][128 * 32];
  __shared__ short Bs[2][128 * 32];
  const int tid = threadIdx.x;
  const int lane = tid & 63;
  const int w = tid >> 6;
  const int orig = blockIdx.x;
  const int xcd = orig & 7, idx = orig >> 3;
  const int rx = xcd & 3, ry = xcd >> 2;
  int bn, bm;
  if (MODE == 2) { bn = ry * 10 + (idx >> 3); bm = rx * 8 + (idx & 7); }  // 20x32
  else           { bn = ry * 8  + (idx >> 3); bm = rx * 8 + (idx & 7); }  // 16x32
  const int wm = (w >> 1) * 64;
  const int l15 = lane & 15, l4 = lane >> 4;
  f32x4 acc[4][4] = {};

  const int sr = lane >> 2;
  const int sp = lane & 3;
  const int nk = K >> 5;

  auto stage = [&](int bi, int kt) {
    const int k0 = kt << 5;
#pragma unroll
    for (int r = 0; r < 2; ++r) {
      const int kb = w + r * 4;
      const int row = kb * 16 + sr;
      const int gcol = (sp ^ ((row >> 1) & 3)) * 8;
      load_lds_16(A + (size_t)(bm * 128 + row) * K + k0 + gcol, &As[bi][kb * 512]);
      load_lds_16(Bw + (size_t)(bn * 128 + row) * K + k0 + gcol, &Bs[bi][kb * 512]);
    }
  };

  stage(0, 0);
  int cur = 0;
  for (int kt = 0; kt < nk; ++kt) {
    if (kt + 1 < nk) {
      stage(cur ^ 1, kt + 1);
      asm volatile("s_waitcnt vmcnt(4)" ::: "memory");
    } else {
      asm volatile("s_waitcnt vmcnt(0)" ::: "memory");
    }
    __builtin_amdgcn_s_barrier();
    asm volatile("" ::: "memory");
    bf16x8 af[4], bfr[4];
#pragma unroll
    for (int i = 0; i < 4; ++i) {
      const int ra = wm + i * 16 + l15;
      af[i] = *(const bf16x8*)&As[cur][ra * 32 + (l4 ^ ((ra >> 1) & 3)) * 8];
      const int rb = (w & 1) * 32 + (i & 1) * 16 + (i >> 1) * 64 + l15;  // paired cols
      bfr[i] = *(const bf16x8*)&Bs[cur][rb * 32 + (l4 ^ ((rb >> 1) & 3)) * 8];
    }
#pragma unroll
    for (int i = 0; i < 4; ++i)
#pragma unroll
      for (int j = 0; j < 4; ++j)
        acc[i][j] = __builtin_amdgcn_mfma_f32_16x16x32_bf16(af[i], bfr[j], acc[i][j], 0, 0, 0);
    asm volatile("" ::: "memory");
    __builtin_amdgcn_s_barrier();
    cur ^= 1;
  }

  if (MODE == 0) {
#pragma unroll
    for (int j = 0; j < 4; ++j) {
      const int n = bn * 128 + (w & 1) * 32 + (j & 1) * 16 + (j >> 1) * 64 + l15;
#pragma unroll
      for (int i = 0; i < 4; ++i) {
        const int mbase = bm * 128 + wm + i * 16 + l4 * 4;
#pragma unroll
        for (int r = 0; r < 4; ++r)
          Cf32[(size_t)(mbase + r) * N + n] = acc[i][j][r];
      }
    }
  } else {
    const int b = bm >> 4;
    if (bn < 18) {
      const bool isq = (bn < 16);
      const float sc = isq ? (0.08838834764831845f * 1.4426950408889634f) : 1.f;
#pragma unroll
      for (int j = 0; j < 2; ++j) {
        const int d = (w & 1) * 32 + j * 16 + l15;        // 0..63
        const int n1 = bn * 128 + d;
        const float b1 = bias[n1];
        const float b2 = bias[n1 + 64];
        short* base;
        if (isq) base = Qo + ((size_t)(b * NH + bn) * S_LEN) * DH;
        else     base = Ko + ((size_t)(b * NKV + (bn - 16)) * S_LEN) * DH;
#pragma unroll
        for (int i = 0; i < 4; ++i) {
          const int sb = (bm & 15) * 128 + wm + i * 16 + l4 * 4;
#pragma unroll
          for (int r = 0; r < 4; ++r) {
            const int s = sb + r;
            const float c  = cosb[s * 128 + d];
            const float sn = sinb[s * 128 + d];
            const float v1 = acc[i][j][r] + b1;
            const float v2 = acc[i][j + 2][r] + b2;
            base[(size_t)s * DH + d]      = f2bf((v1 * c - v2 * sn) * sc);
            base[(size_t)s * DH + d + 64] = f2bf((v2 * c + v1 * sn) * sc);
          }
        }
      }
    } else {
      const int kv = bn - 18;
      short* vbase = VT + (size_t)(b * NKV + kv) * DH * S_LEN;
#pragma unroll
      for (int j = 0; j < 4; ++j) {
        const int d = (w & 1) * 32 + (j & 1) * 16 + (j >> 1) * 64 + l15;  // 0..127
        const float bv = bias[bn * 128 + d];
#pragma unroll
        for (int i = 0; i < 4; ++i) {
          const int sb = (bm & 15) * 128 + wm + i * 16 + l4 * 4;
          short4 st;
          st.x = f2bf(acc[i][j][0] + bv);
          st.y = f2bf(acc[i][j][1] + bv);
          st.z = f2bf(acc[i][j][2] + bv);
          st.w = f2bf(acc[i][j][3] + bv);
          *(short4*)(vbase + (size_t)d * S_LEN + sb) = st;
        }
      }
    }
  }
}

// ---------------- causal GQA flash attention (R17-proven: K single, V dbuf) -----
// XCD-grouped grid: bh = xcd*4 + (idx&3) -> each XCD touches only 4 bh-groups
// (K+V 4MB = one XCD L2); both kv-parities of a (bh,x) land on the same XCD
// (Q second read = L2 hit). Longest-first within each XCD. Bijective remap.
template<int NS>
__global__ __launch_bounds__(256, 2) void attn_k(
    const short* __restrict__ Qb, const short* __restrict__ Kb,
    const short* __restrict__ VTb, short* __restrict__ Opart,
    float2* __restrict__ ML) {
  __shared__ short Ks[64 * 128];
  __shared__ short Vs[2][128 * 64];
  const int tid = threadIdx.x, lane = tid & 63, w = tid >> 6;
  const int orig = blockIdx.x;           // 0..1023 (NS=2)
  const int xcd = orig & 7, idx = orig >> 3;        // idx 0..127
  const int bh = xcd * 4 + (idx & 3);    // 4 bh-groups per XCD
  const int z = idx >> 2;                // 0..31
  const int s = z & 1;                   // kv parity
  const int xo = z >> 1;                 // 0..15
  const int x = 15 - xo;                 // longest blocks first (per XCD)
  const int b = bh >> 4, h = bh & 15;
  const int kvh = h >> 3;
  const int l31 = lane & 31, hi = lane >> 5;
  const int qw = x * 128 + w * 32;
  const int q = qw + l31;
  const int num = 2 * x + 2 - s;
  const int cnt = num > 0 ? (num + NS - 1) / NS : 0;

  const short* Kbase = Kb + (size_t)(b * NKV + kvh) * S_LEN * DH;
  const short* Vbase = VTb + (size_t)(b * NKV + kvh) * DH * S_LEN;

  auto stageK = [&](int tile) {
    const int kv0 = tile << 6;
#pragma unroll
    for (int r = 0; r < 4; ++r) {
      const int kb = r * 4 + w;
      const int krow = kb * 4 + (lane >> 4);
      const int gs = ((lane & 15) ^ (krow & 15)) * 8;
      load_lds_16(Kbase + (size_t)(kv0 + krow) * DH + gs, &Ks[kb * 512]);
    }
  };
  auto stageV = [&](int bi, int tile) {
    const int kv0 = tile << 6;
#pragma unroll
    for (int r = 0; r < 4; ++r) {
      const int kb = r * 4 + w;
      const int vrow = kb * 8 + (lane >> 3);
      const int gs = ((lane & 7) ^ (vrow & 7)) * 8;
      load_lds_16(Vbase + (size_t)vrow * S_LEN + kv0 + gs, &Vs[bi][kb * 512]);
    }
  };

  f32x16 o[4] = {};   // O^T tiles: o[dt][r] = O[q][d=(r&3)+8*(r>>2)+4hi+32dt]
  float m_r = -1e30f, l_r = 0.f;

  if (cnt > 0) {
    bf16x8 qf[8];
    {
      const short* qrow = Qb + ((size_t)(b * NH + h) * S_LEN + q) * DH;
#pragma unroll
      for (int ss = 0; ss < 8; ++ss)
        qf[ss] = *(const bf16x8*)(qrow + ss * 16 + hi * 8);
    }
    stageK(s);        // K_0 (4 loads, oldest)
    stageV(0, s);     // V_0 (4 loads)
    int cur = 0;
    for (int j = 0; j < cnt; ++j) {
      const int tile = s + NS * j;
      const int kv0 = tile << 6;
      const bool more = (j + 1 < cnt);
      const bool active = (kv0 <= qw + 31);
      asm volatile("s_waitcnt vmcnt(4)" ::: "memory");
      __builtin_amdgcn_s_barrier();                       // bar1: K_j global
      asm volatile("" ::: "memory");
      f32x16 sc0 = {}, sc1 = {};
      if (active) {
        __builtin_amdgcn_s_setprio(1);
#pragma unroll
        for (int ss = 0; ss < 8; ++ss) {
          const int sl = ((2 * ss + hi) ^ (l31 & 15)) * 8;
          const bf16x8 kf0 = *(const bf16x8*)&Ks[l31 * 128 + sl];
          const bf16x8 kf1 = *(const bf16x8*)&Ks[(l31 + 32) * 128 + sl];
          sc0 = __builtin_amdgcn_mfma_f32_32x32x16_bf16(kf0, qf[ss], sc0, 0, 0, 0);
          sc1 = __builtin_amdgcn_mfma_f32_32x32x16_bf16(kf1, qf[ss], sc1, 0, 0, 0);
        }
        __builtin_amdgcn_s_setprio(0);
      }
      asm volatile("s_waitcnt vmcnt(0)" ::: "memory");
      asm volatile("" ::: "memory");
      __builtin_amdgcn_s_barrier();                       // bar2: K free + V_j global
      if (more) {
        stageK(tile + NS);
        stageV(cur ^ 1, tile + NS);
      }
      if (active) {
        if (kv0 + 63 > qw) {
#pragma unroll
          for (int r = 0; r < 16; ++r) {
            const int kva = kv0 + (r & 3) + 8 * (r >> 2) + 4 * hi;
            if (kva > q) sc0[r] = -1e30f;
            if (kva + 32 > q) sc1[r] = -1e30f;
          }
        }
        float mx[16];
#pragma unroll
        for (int r = 0; r < 16; ++r) mx[r] = fmaxf(sc0[r], sc1[r]);
#pragma unroll
        for (int st = 8; st >= 1; st >>= 1)
#pragma unroll
          for (int r = 0; r < st; ++r) mx[r] = fmaxf(mx[r], mx[r + st]);
        const float pm = fmaxf(mx[0], __shfl_xor(mx[0], 32));
        if (__any(pm > m_r + 8.f)) {   // T13 defer-rescale
          const float nm = fmaxf(m_r, pm);
          const float fr = exp2f(m_r - nm);
          l_r *= fr;
#pragma unroll
          for (int dt = 0; dt < 4; ++dt)
#pragma unroll
            for (int r = 0; r < 16; ++r)
              o[dt][r] *= fr;
          m_r = nm;
        }
#pragma unroll
        for (int r = 0; r < 16; ++r) {
          sc0[r] = exp2f(sc0[r] - m_r);
          sc1[r] = exp2f(sc1[r] - m_r);
        }
        float sm[16];
#pragma unroll
        for (int r = 0; r < 16; ++r) sm[r] = sc0[r] + sc1[r];
#pragma unroll
        for (int st = 8; st >= 1; st >>= 1)
#pragma unroll
          for (int r = 0; r < st; ++r) sm[r] += sm[r + st];
        l_r += sm[0] + __shfl_xor(sm[0], 32);
        u32 e0 = cvt_pk_bf16(sc0[0], sc0[1]),  e1 = cvt_pk_bf16(sc0[2], sc0[3]);
        u32 e2 = cvt_pk_bf16(sc0[4], sc0[5]),  e3 = cvt_pk_bf16(sc0[6], sc0[7]);
        u32 e4 = cvt_pk_bf16(sc0[8], sc0[9]),  e5 = cvt_pk_bf16(sc0[10], sc0[11]);
        u32 e6 = cvt_pk_bf16(sc0[12], sc0[13]), e7 = cvt_pk_bf16(sc0[14], sc0[15]);
        u32 f0 = cvt_pk_bf16(sc1[0], sc1[1]),  f1 = cvt_pk_bf16(sc1[2], sc1[3]);
        u32 f2 = cvt_pk_bf16(sc1[4], sc1[5]),  f3 = cvt_pk_bf16(sc1[6], sc1[7]);
        u32 f4 = cvt_pk_bf16(sc1[8], sc1[9]),  f5 = cvt_pk_bf16(sc1[10], sc1[11]);
        u32 f6 = cvt_pk_bf16(sc1[12], sc1[13]), f7 = cvt_pk_bf16(sc1[14], sc1[15]);
        asm("v_permlane32_swap_b32 %0, %1" : "+v"(e0), "+v"(e2));
        asm("v_permlane32_swap_b32 %0, %1" : "+v"(e1), "+v"(e3));
        asm("v_permlane32_swap_b32 %0, %1" : "+v"(e4), "+v"(e6));
        asm("v_permlane32_swap_b32 %0, %1" : "+v"(e5), "+v"(e7));
        asm("v_permlane32_swap_b32 %0, %1" : "+v"(f0), "+v"(f2));
        asm("v_permlane32_swap_b32 %0, %1" : "+v"(f1), "+v"(f3));
        asm("v_permlane32_swap_b32 %0, %1" : "+v"(f4), "+v"(f6));
        asm("v_permlane32_swap_b32 %0, %1" : "+v"(f5), "+v"(f7));
        union { u32 u[4]; bf16x8 v; } pk0, pk1, pk2, pk3;
        pk0.u[0] = e0; pk0.u[1] = e1; pk0.u[2] = e2; pk0.u[3] = e3;  // kv 0..15
        pk1.u[0] = e4; pk1.u[1] = e5; pk1.u[2] = e6; pk1.u[3] = e7;  // kv 16..31
        pk2.u[0] = f0; pk2.u[1] = f1; pk2.u[2] = f2; pk2.u[3] = f3;  // kv 32..47
        pk3.u[0] = f4; pk3.u[1] = f5; pk3.u[2] = f6; pk3.u[3] = f7;  // kv 48..63
        const bf16x8 pa[4] = {pk0.v, pk1.v, pk2.v, pk3.v};
        __builtin_amdgcn_s_setprio(1);
#pragma unroll
        for (int ss = 0; ss < 4; ++ss) {
#pragma unroll
          for (int dt = 0; dt < 4; ++dt) {
            const int row = dt * 32 + l31;
            const int sl = ((2 * ss + hi) ^ (l31 & 7)) * 8;
            const bf16x8 vf = *(const bf16x8*)&Vs[cur][row * 64 + sl];
            o[dt] = __builtin_amdgcn_mfma_f32_32x32x16_bf16(vf, pa[ss], o[dt], 0, 0, 0);
          }
        }
        __builtin_amdgcn_s_setprio(0);
      }
      cur ^= 1;
    }
  }

  const int T = (bh * 16 + x) * NS + s;
  const int ql = w * 32 + l31;
  short* orow = Opart + (size_t)T * 16384 + ql * 128;
#pragma unroll
  for (int dt = 0; dt < 4; ++dt)
#pragma unroll
    for (int gg = 0; gg < 4; ++gg) {
      short4 st;
      st.x = f2bf(o[dt][4 * gg + 0]);
      st.y = f2bf(o[dt][4 * gg + 1]);
      st.z = f2bf(o[dt][4 * gg + 2]);
      st.w = f2bf(o[dt][4 * gg + 3]);
      *(short4*)(orow + dt * 32 + 8 * gg + 4 * hi) = st;
    }
  if (hi == 0) ML[T * 128 + ql] = make_float2(m_r, l_r);
}

// ---------------- combine the NS kv-split partials ----------------
template<int NS>
__global__ void combine_k(const short* __restrict__ Opart,
                          const float2* __restrict__ ML,
                          short* __restrict__ att_o) {
  const int t = blockIdx.x * 256 + threadIdx.x;   // 2^20 threads
  const int d8 = t & 15;
  const int h  = (t >> 4) & 15;
  const int q  = (t >> 8) & 2047;
  const int b  = t >> 19;
  const int bh = b * 16 + h;
  const int x = q >> 7, ql = q & 127;
  const int T0 = (bh * 16 + x) * NS;
  float2 a[NS];
  float ms = -1e30f;
#pragma unroll
  for (int i = 0; i < NS; ++i) {
    a[i] = ML[(T0 + i) * 128 + ql];
    ms = fmaxf(ms, a[i].x);
  }
  float wgt[NS];
  float den = 0.f;
#pragma unroll
  for (int i = 0; i < NS; ++i) {
    wgt[i] = exp2f(a[i].x - ms);
    den += a[i].y * wgt[i];
  }
  const float inv = 1.f / den;
  float acc[8] = {};
#pragma unroll
  for (int i = 0; i < NS; ++i) {
    const bf16x8 oi = *(const bf16x8*)(Opart + (size_t)(T0 + i) * 16384 + ql * 128 + d8 * 8);
#pragma unroll
    for (int e = 0; e < 8; ++e)
      acc[e] += bf2f(oi[e]) * wgt[i];
  }
  bf16x8 res;
#pragma unroll
  for (int e = 0; e < 8; ++e)
    res[e] = f2bf(acc[e] * inv);
  *(bf16x8*)(att_o + (size_t)(b * S_LEN + q) * (NH * DH) + h * DH + d8 * 8) = res;
}

// ---------------- launch ----------------
extern "C" void kernel_launch(void* const* d_in, const int* in_sizes, int n_in,
                              void* d_out, int out_size, void* d_ws, size_t ws_size,
                              hipStream_t stream) {
  const float* hid  = (const float*)d_in[0];
  const float* cosb = (const float*)d_in[1];
  const float* sinb = (const float*)d_in[2];
  const float* q_w  = (const float*)d_in[3];
  const float* q_b  = (const float*)d_in[4];
  const float* k_w  = (const float*)d_in[5];
  const float* k_b  = (const float*)d_in[6];
  const float* v_w  = (const float*)d_in[7];
  const float* v_b  = (const float*)d_in[8];
  const float* o_w  = (const float*)d_in[9];
  (void)in_sizes; (void)n_in; (void)out_size; (void)ws_size;

  char* ws = (char*)d_ws;
  short*  x_bf   = (short*)(ws + 0);           // [4096][2048] (phase 1)
  short*  w_bf   = (short*)(ws + 16777216);    // [2560][2048] (phase 1)
  short*  Opart  = (short*)(ws + 0);           // [1024][16384] (attn phase; overlays x/w)
  float2* MLbuf  = (float2*)(ws + 33554432);
  float*  biasc  = (float*)(ws + 35651584);
  short*  q_bf   = (short*)(ws + 35667968);    // [B][H][S][D] (roped, scaled)
  short*  ow_bf  = (short*)(ws + 56639488);    // [2048][2048]
  short*  k_bf   = (short*)(ws + 73416704);    // [B][KV][S][D] (roped)
  short*  vT_bf  = (short*)(ws + 75513856);    // [B][KV][D][S]
  short*  att_o  = (short*)(ws + 77611008);    // [4096][2048]

  hipLaunchKernelGGL(megacvt_k, dim3(17418), dim3(256), 0, stream,
                     hid, q_w, k_w, v_w, o_w, q_b, k_b, v_b, x_bf, w_bf, ow_bf, biasc);
  hipLaunchKernelGGL((gemm_nt_k<2>), dim3(640), dim3(256), 0, stream,
                     x_bf, w_bf, biasc, cosb, sinb,
                     (float*)nullptr, q_bf, k_bf, vT_bf, 4096, 2560, 2048);
  hipLaunchKernelGGL(attn_k<2>, dim3(1024), dim3(256), 0, stream,
                     q_bf, k_bf, vT_bf, Opart, MLbuf);
  hipLaunchKernelGGL(combine_k<2>, dim3(4096), dim3(256), 0, stream, Opart, MLbuf, att_o);
  hipLaunchKernelGGL((gemm_nt_k<0>), dim3(512), dim3(256), 0, stream,
                     att_o, ow_bf, (const float*)nullptr, (const float*)nullptr,
                     (const float*)nullptr, (float*)d_out,
                     (short*)nullptr, (short*)nullptr, (short*)nullptr, 4096, 2048, 2048);
}